// Round 1
// baseline (447.243 us; speedup 1.0000x reference)
//
#include <hip/hip_runtime.h>
#include <math.h>

#define B_ROWS 512
#define D_DIM  512
#define C_CLS  100000
#define SCALE  64.0f
#define EPSN   1e-12f

#define BM 128
#define BN 128
#define BK 32
#define NTILE 782           // ceil(100000/128)
#define NT2   (NTILE*2)     // partials per row (one per 64-col wave slice)

typedef __attribute__((ext_vector_type(8))) short bf16x8;
typedef __attribute__((ext_vector_type(4))) float f32x4;

__device__ inline unsigned short f2bf(float f) {
    union { float f; unsigned int u; } v; v.f = f;
    unsigned int r = v.u + 0x7fffu + ((v.u >> 16) & 1u);
    return (unsigned short)(r >> 16);
}
__device__ inline float bf2f(unsigned short h) {
    union { unsigned int u; float f; } v; v.u = ((unsigned int)h) << 16;
    return v.f;
}

// ---------- Kernel A: normalize x rows, store bf16 ----------
__global__ void normalize_x(const float* __restrict__ x, unsigned short* __restrict__ xnb) {
    int row  = blockIdx.x;
    int lane = threadIdx.x;  // 64
    const float4* xr = (const float4*)(x + (size_t)row * D_DIM);
    float4 a = xr[lane * 2];
    float4 b = xr[lane * 2 + 1];
    float ss = a.x*a.x + a.y*a.y + a.z*a.z + a.w*a.w
             + b.x*b.x + b.y*b.y + b.z*b.z + b.w*b.w;
    #pragma unroll
    for (int m = 1; m < 64; m <<= 1) ss += __shfl_xor(ss, m);
    float inv = 1.0f / fmaxf(sqrtf(ss), EPSN);
    ushort4 o0, o1;
    o0.x = f2bf(a.x*inv); o0.y = f2bf(a.y*inv); o0.z = f2bf(a.z*inv); o0.w = f2bf(a.w*inv);
    o1.x = f2bf(b.x*inv); o1.y = f2bf(b.y*inv); o1.z = f2bf(b.z*inv); o1.w = f2bf(b.w*inv);
    ushort4* orow = (ushort4*)(xnb + (size_t)row * D_DIM);
    orow[lane * 2]     = o0;
    orow[lane * 2 + 1] = o1;
}

// ---------- Kernel B: per-class inverse norms (scaled by S) ----------
__global__ void w_norms(const float* __restrict__ w, float* __restrict__ winv) {
    int c    = blockIdx.x * 4 + (threadIdx.x >> 6);
    int lane = threadIdx.x & 63;
    const float4* wr = (const float4*)(w + (size_t)c * D_DIM);
    float4 a = wr[lane * 2];
    float4 b = wr[lane * 2 + 1];
    float ss = a.x*a.x + a.y*a.y + a.z*a.z + a.w*a.w
             + b.x*b.x + b.y*b.y + b.z*b.z + b.w*b.w;
    #pragma unroll
    for (int m = 1; m < 64; m <<= 1) ss += __shfl_xor(ss, m);
    if (lane == 0) winv[c] = SCALE / fmaxf(sqrtf(ss), EPSN);
}

// ---------- Kernel C: bf16 MFMA GEMM + fused partial softmax ----------
__global__ __launch_bounds__(256) void gemm_ce(const unsigned short* __restrict__ xnb,
                                               const float* __restrict__ w,
                                               const float* __restrict__ winv,
                                               float2* __restrict__ partials) {
    __shared__ unsigned short As[BM * BK];  // 8 KB
    __shared__ unsigned short Bs[BN * BK];  // 8 KB

    int tid  = threadIdx.x;
    int m0   = blockIdx.x * BM;   // 4 m-tiles
    int c0   = blockIdx.y * BN;   // 782 n-tiles
    int wid  = tid >> 6;
    int lane = tid & 63;
    int quad = lane >> 4;
    int lr   = lane & 15;
    int wr   = wid >> 1;          // wave row (0..1): 64 rows
    int wc   = wid & 1;           // wave col (0..1): 64 cols

    f32x4 acc[4][4];
    #pragma unroll
    for (int i = 0; i < 4; i++)
        #pragma unroll
        for (int j = 0; j < 4; j++) {
            acc[i][j][0] = 0.f; acc[i][j][1] = 0.f; acc[i][j][2] = 0.f; acc[i][j][3] = 0.f;
        }

    // B staging assignment: 8 float4-chunks per 32-float row; 32 rows per pass, 4 passes
    int q     = tid & 7;
    int rbase = tid >> 3;

    for (int kt = 0; kt < D_DIM / BK; ++kt) {
        int k0 = kt * BK;
        __syncthreads();
        // stage A (bf16, copy 16B chunks): chunk ch -> row=ch>>2, ko=(ch&3)*8
        {
            int ch0 = tid, ch1 = tid + 256;
            uint4 v0 = *(const uint4*)(xnb + (size_t)(m0 + (ch0 >> 2)) * D_DIM + k0 + (ch0 & 3) * 8);
            uint4 v1 = *(const uint4*)(xnb + (size_t)(m0 + (ch1 >> 2)) * D_DIM + k0 + (ch1 & 3) * 8);
            ((uint4*)As)[ch0] = v0;
            ((uint4*)As)[ch1] = v1;
        }
        // stage B (fp32 -> bf16 convert)
        #pragma unroll
        for (int it = 0; it < 4; ++it) {
            int r = rbase + it * 32;
            int c = c0 + r;
            if (c >= C_CLS) c = C_CLS - 1;   // clamp; masked in epilogue
            float4 wv = *(const float4*)(w + (size_t)c * D_DIM + k0 + q * 4);
            ushort4 o;
            o.x = f2bf(wv.x); o.y = f2bf(wv.y); o.z = f2bf(wv.z); o.w = f2bf(wv.w);
            *(ushort4*)(Bs + r * BK + q * 4) = o;
        }
        __syncthreads();

        bf16x8 af[4], bf[4];
        #pragma unroll
        for (int i = 0; i < 4; i++)
            af[i] = *(const bf16x8*)(As + (wr * 64 + i * 16 + lr) * BK + quad * 8);
        #pragma unroll
        for (int j = 0; j < 4; j++)
            bf[j] = *(const bf16x8*)(Bs + (wc * 64 + j * 16 + lr) * BK + quad * 8);
        #pragma unroll
        for (int i = 0; i < 4; i++)
            #pragma unroll
            for (int j = 0; j < 4; j++)
                acc[i][j] = __builtin_amdgcn_mfma_f32_16x16x32_bf16(af[i], bf[j], acc[i][j], 0, 0, 0);
    }

    // epilogue: scale by winv, per-row online-softmax partial over this wave's 64 cols
    float wv[4];
    int valid[4];
    #pragma unroll
    for (int j = 0; j < 4; j++) {
        int cg = c0 + wc * 64 + j * 16 + lr;
        valid[j] = (cg < C_CLS);
        wv[j] = winv[valid[j] ? cg : (C_CLS - 1)];
    }
    int tile2 = blockIdx.y * 2 + wc;
    #pragma unroll
    for (int i = 0; i < 4; i++) {
        #pragma unroll
        for (int r = 0; r < 4; r++) {
            int row_g = m0 + wr * 64 + i * 16 + quad * 4 + r;
            float v0 = valid[0] ? acc[i][0][r] * wv[0] : -1e30f;
            float v1 = valid[1] ? acc[i][1][r] * wv[1] : -1e30f;
            float v2 = valid[2] ? acc[i][2][r] * wv[2] : -1e30f;
            float v3 = valid[3] ? acc[i][3][r] * wv[3] : -1e30f;
            float m = fmaxf(fmaxf(v0, v1), fmaxf(v2, v3));
            #pragma unroll
            for (int msk = 1; msk < 16; msk <<= 1) m = fmaxf(m, __shfl_xor(m, msk));
            float s = expf(v0 - m) + expf(v1 - m) + expf(v2 - m) + expf(v3 - m);
            #pragma unroll
            for (int msk = 1; msk < 16; msk <<= 1) s += __shfl_xor(s, msk);
            if (lr == 0)
                partials[(size_t)row_g * NT2 + tile2] = make_float2(m, s);
        }
    }
}

// ---------- Kernel E: logit at label (bf16 xhat . fp32 w_label * winv) ----------
__global__ void label_logit(const unsigned short* __restrict__ xnb,
                            const float* __restrict__ w,
                            const float* __restrict__ winv,
                            const int* __restrict__ label,
                            float* __restrict__ t) {
    int b = blockIdx.x;
    int lane = threadIdx.x;  // 64
    int lab = label[b];
    const float4*  wr = (const float4*)(w + (size_t)lab * D_DIM);
    const ushort4* xr = (const ushort4*)(xnb + (size_t)b * D_DIM);
    float dot = 0.f;
    #pragma unroll
    for (int k = 0; k < 2; k++) {
        float4  wv = wr[lane * 2 + k];
        ushort4 xv = xr[lane * 2 + k];
        dot += bf2f(xv.x) * wv.x + bf2f(xv.y) * wv.y + bf2f(xv.z) * wv.z + bf2f(xv.w) * wv.w;
    }
    #pragma unroll
    for (int m = 1; m < 64; m <<= 1) dot += __shfl_xor(dot, m);
    if (lane == 0) t[b] = dot * winv[lab];
}

// ---------- Kernel D: merge partials -> LSE -> mean NLL ----------
__global__ void reduce_loss(const float2* __restrict__ partials,
                            const float* __restrict__ t,
                            float* __restrict__ out) {
    __shared__ float sm[256], ssum[256];
    int row = blockIdx.x, tid = threadIdx.x;
    float m = -INFINITY, s = 0.f;
    for (int idx = tid; idx < NT2; idx += 256) {
        float2 p = partials[(size_t)row * NT2 + idx];
        if (p.x > m) { s = s * expf(m - p.x) + p.y; m = p.x; }
        else         { s += p.y * expf(p.x - m); }
    }
    sm[tid] = m; ssum[tid] = s;
    __syncthreads();
    for (int off = 128; off > 0; off >>= 1) {
        if (tid < off) {
            float m2 = sm[tid + off], s2 = ssum[tid + off];
            float mm = fmaxf(m, m2);
            s = s * expf(m - mm) + s2 * expf(m2 - mm);
            m = mm;
            sm[tid] = m; ssum[tid] = s;
        }
        __syncthreads();
    }
    if (tid == 0) {
        float lse = m + logf(s);
        atomicAdd(out, (lse - t[row]) * (1.0f / (float)B_ROWS));
    }
}

extern "C" void kernel_launch(void* const* d_in, const int* in_sizes, int n_in,
                              void* d_out, int out_size, void* d_ws, size_t ws_size,
                              hipStream_t stream) {
    const float* x     = (const float*)d_in[0];
    const float* w     = (const float*)d_in[1];
    const int*   label = (const int*)d_in[2];
    float* out = (float*)d_out;

    char* ws = (char*)d_ws;
    unsigned short* xnb = (unsigned short*)ws;                 // 512*512*2   = 524288 B
    float* winv         = (float*)(ws + 524288);               // 100000*4    = 400000 B
    float* t            = (float*)(ws + 924288);               // 512*4       = 2048 B
    float2* partials    = (float2*)(ws + 926336);              // 512*1564*8  = 6406144 B
    // total ~7.3 MB of ws

    hipMemsetAsync(d_out, 0, sizeof(float), stream);
    normalize_x<<<B_ROWS, 64, 0, stream>>>(x, xnb);
    w_norms<<<C_CLS / 4, 256, 0, stream>>>(w, winv);
    gemm_ce<<<dim3(4, NTILE), 256, 0, stream>>>(xnb, w, winv, partials);
    label_logit<<<B_ROWS, 64, 0, stream>>>(xnb, w, winv, label, t);
    reduce_loss<<<B_ROWS, 256, 0, stream>>>(partials, t, out);
}

// Round 2
// 416.767 us; speedup vs baseline: 1.0731x; 1.0731x over previous
//
#include <hip/hip_runtime.h>
#include <math.h>

#define B_ROWS 512
#define D_DIM  512
#define C_CLS  100000
#define SCALE  64.0f
#define EPSN   1e-12f

#define BM 128
#define BN 128
#define BK 32
#define NTILE 782           // ceil(100000/128)
#define NT2   (NTILE*2)     // partials per row (one per 64-col wave slice)

typedef __attribute__((ext_vector_type(8))) short bf16x8;
typedef __attribute__((ext_vector_type(4))) float f32x4;

__device__ inline unsigned short f2bf(float f) {
    union { float f; unsigned int u; } v; v.f = f;
    unsigned int r = v.u + 0x7fffu + ((v.u >> 16) & 1u);
    return (unsigned short)(r >> 16);
}
__device__ inline float bf2f(unsigned short h) {
    union { unsigned int u; float f; } v; v.u = ((unsigned int)h) << 16;
    return v.f;
}

// ---------- normalize x rows, store bf16 (coalesced: lane, lane+64) ----------
__global__ void normalize_x(const float* __restrict__ x, unsigned short* __restrict__ xnb) {
    int row  = blockIdx.x;
    int lane = threadIdx.x;  // 64
    const float4* xr = (const float4*)(x + (size_t)row * D_DIM);
    float4 a = xr[lane];
    float4 b = xr[lane + 64];
    float ss = a.x*a.x + a.y*a.y + a.z*a.z + a.w*a.w
             + b.x*b.x + b.y*b.y + b.z*b.z + b.w*b.w;
    #pragma unroll
    for (int m = 1; m < 64; m <<= 1) ss += __shfl_xor(ss, m);
    float inv = 1.0f / fmaxf(sqrtf(ss), EPSN);
    ushort4 o0, o1;
    o0.x = f2bf(a.x*inv); o0.y = f2bf(a.y*inv); o0.z = f2bf(a.z*inv); o0.w = f2bf(a.w*inv);
    o1.x = f2bf(b.x*inv); o1.y = f2bf(b.y*inv); o1.z = f2bf(b.z*inv); o1.w = f2bf(b.w*inv);
    ushort4* orow = (ushort4*)(xnb + (size_t)row * D_DIM);
    orow[lane]      = o0;
    orow[lane + 64] = o1;
}

// ---------- W prep: wn[c,:] = w[c,:] * S / ||w[c,:]||, bf16 ----------
__global__ void w_prep(const float* __restrict__ w, unsigned short* __restrict__ wn) {
    int c    = blockIdx.x * 4 + (threadIdx.x >> 6);
    int lane = threadIdx.x & 63;
    const float4* wr = (const float4*)(w + (size_t)c * D_DIM);
    float4 a = wr[lane];
    float4 b = wr[lane + 64];
    float ss = a.x*a.x + a.y*a.y + a.z*a.z + a.w*a.w
             + b.x*b.x + b.y*b.y + b.z*b.z + b.w*b.w;
    #pragma unroll
    for (int m = 1; m < 64; m <<= 1) ss += __shfl_xor(ss, m);
    float s = SCALE / fmaxf(sqrtf(ss), EPSN);
    ushort4 o0, o1;
    o0.x = f2bf(a.x*s); o0.y = f2bf(a.y*s); o0.z = f2bf(a.z*s); o0.w = f2bf(a.w*s);
    o1.x = f2bf(b.x*s); o1.y = f2bf(b.y*s); o1.z = f2bf(b.z*s); o1.w = f2bf(b.w*s);
    ushort4* orow = (ushort4*)(wn + (size_t)c * D_DIM);
    orow[lane]      = o0;
    orow[lane + 64] = o1;
}

// ---------- bf16 MFMA GEMM (global_load_lds staging) + fused partial softmax ----------
__global__ __launch_bounds__(256) void gemm_ce(const unsigned short* __restrict__ xnb,
                                               const unsigned short* __restrict__ wn,
                                               float2* __restrict__ partials) {
    __shared__ unsigned short As[BM * BK];  // 8 KB
    __shared__ unsigned short Bs[BN * BK];  // 8 KB

    int tid  = threadIdx.x;
    int m0   = blockIdx.x * BM;
    int c0   = blockIdx.y * BN;
    int wid  = tid >> 6;
    int lane = tid & 63;
    int quad = lane >> 4;
    int lr   = lane & 15;
    int wr   = wid >> 1;
    int wc   = wid & 1;

    f32x4 acc[4][4];
    #pragma unroll
    for (int i = 0; i < 4; i++)
        #pragma unroll
        for (int j = 0; j < 4; j++) {
            acc[i][j][0] = 0.f; acc[i][j][1] = 0.f; acc[i][j][2] = 0.f; acc[i][j][3] = 0.f;
        }

    // staging chunk ids: 16B chunks, row = ch>>2, k-off = (ch&3)*8 (ushorts)
    int ch0 = tid;            // pass 0
    int ch1 = tid + 256;      // pass 1
    int ar0 = m0 + (ch0 >> 2), ao0 = (ch0 & 3) * 8;
    int ar1 = m0 + (ch1 >> 2), ao1 = (ch1 & 3) * 8;
    int bc0 = c0 + (ch0 >> 2); if (bc0 >= C_CLS) bc0 = C_CLS - 1;
    int bc1 = c0 + (ch1 >> 2); if (bc1 >= C_CLS) bc1 = C_CLS - 1;
    int bo0 = (ch0 & 3) * 8, bo1 = (ch1 & 3) * 8;

    // wave-uniform LDS bases: lane writes base + lane*16
    unsigned short* asb0 = As + wid * 512;            // bytes: wid*1024
    unsigned short* asb1 = As + 2048 + wid * 512;     // + 4096 B
    unsigned short* bsb0 = Bs + wid * 512;
    unsigned short* bsb1 = Bs + 2048 + wid * 512;

    for (int kt = 0; kt < D_DIM / BK; ++kt) {
        int k0 = kt * BK;
        __syncthreads();
        __builtin_amdgcn_global_load_lds(
            (const __attribute__((address_space(1))) void*)(xnb + (size_t)ar0 * D_DIM + k0 + ao0),
            (__attribute__((address_space(3))) void*)asb0, 16, 0, 0);
        __builtin_amdgcn_global_load_lds(
            (const __attribute__((address_space(1))) void*)(xnb + (size_t)ar1 * D_DIM + k0 + ao1),
            (__attribute__((address_space(3))) void*)asb1, 16, 0, 0);
        __builtin_amdgcn_global_load_lds(
            (const __attribute__((address_space(1))) void*)(wn + (size_t)bc0 * D_DIM + k0 + bo0),
            (__attribute__((address_space(3))) void*)bsb0, 16, 0, 0);
        __builtin_amdgcn_global_load_lds(
            (const __attribute__((address_space(1))) void*)(wn + (size_t)bc1 * D_DIM + k0 + bo1),
            (__attribute__((address_space(3))) void*)bsb1, 16, 0, 0);
        __syncthreads();

        bf16x8 af[4], bf[4];
        #pragma unroll
        for (int i = 0; i < 4; i++)
            af[i] = *(const bf16x8*)(As + (wr * 64 + i * 16 + lr) * BK + quad * 8);
        #pragma unroll
        for (int j = 0; j < 4; j++)
            bf[j] = *(const bf16x8*)(Bs + (wc * 64 + j * 16 + lr) * BK + quad * 8);
        #pragma unroll
        for (int i = 0; i < 4; i++)
            #pragma unroll
            for (int j = 0; j < 4; j++)
                acc[i][j] = __builtin_amdgcn_mfma_f32_16x16x32_bf16(af[i], bf[j], acc[i][j], 0, 0, 0);
    }

    // epilogue: per-row online-softmax partial over this wave's 64 cols (already scaled)
    int valid[4];
    #pragma unroll
    for (int j = 0; j < 4; j++)
        valid[j] = (c0 + wc * 64 + j * 16 + lr) < C_CLS;
    int tile2 = blockIdx.y * 2 + wc;
    #pragma unroll
    for (int i = 0; i < 4; i++) {
        #pragma unroll
        for (int r = 0; r < 4; r++) {
            int row_g = m0 + wr * 64 + i * 16 + quad * 4 + r;
            float v0 = valid[0] ? acc[i][0][r] : -1e30f;
            float v1 = valid[1] ? acc[i][1][r] : -1e30f;
            float v2 = valid[2] ? acc[i][2][r] : -1e30f;
            float v3 = valid[3] ? acc[i][3][r] : -1e30f;
            float m = fmaxf(fmaxf(v0, v1), fmaxf(v2, v3));
            #pragma unroll
            for (int msk = 1; msk < 16; msk <<= 1) m = fmaxf(m, __shfl_xor(m, msk));
            float s = expf(v0 - m) + expf(v1 - m) + expf(v2 - m) + expf(v3 - m);
            #pragma unroll
            for (int msk = 1; msk < 16; msk <<= 1) s += __shfl_xor(s, msk);
            if (lr == 0)
                partials[(size_t)row_g * NT2 + tile2] = make_float2(m, s);
        }
    }
}

// ---------- label logit from bf16 operands (consistent with GEMM) ----------
__global__ void label_logit(const unsigned short* __restrict__ xnb,
                            const unsigned short* __restrict__ wn,
                            const int* __restrict__ label,
                            float* __restrict__ t) {
    int b = blockIdx.x;
    int lane = threadIdx.x;  // 64
    int lab = label[b];
    const ushort4* wr = (const ushort4*)(wn + (size_t)lab * D_DIM);
    const ushort4* xr = (const ushort4*)(xnb + (size_t)b * D_DIM);
    float dot = 0.f;
    #pragma unroll
    for (int k = 0; k < 2; k++) {
        ushort4 wv = wr[lane + 64 * k];
        ushort4 xv = xr[lane + 64 * k];
        dot += bf2f(xv.x) * bf2f(wv.x) + bf2f(xv.y) * bf2f(wv.y)
             + bf2f(xv.z) * bf2f(wv.z) + bf2f(xv.w) * bf2f(wv.w);
    }
    #pragma unroll
    for (int m = 1; m < 64; m <<= 1) dot += __shfl_xor(dot, m);
    if (lane == 0) t[b] = dot;
}

// ---------- merge partials -> LSE -> mean NLL ----------
__global__ void reduce_loss(const float2* __restrict__ partials,
                            const float* __restrict__ t,
                            float* __restrict__ out) {
    __shared__ float sm[256], ssum[256];
    int row = blockIdx.x, tid = threadIdx.x;
    float m = -INFINITY, s = 0.f;
    for (int idx = tid; idx < NT2; idx += 256) {
        float2 p = partials[(size_t)row * NT2 + idx];
        if (p.x > m) { s = s * expf(m - p.x) + p.y; m = p.x; }
        else         { s += p.y * expf(p.x - m); }
    }
    sm[tid] = m; ssum[tid] = s;
    __syncthreads();
    for (int off = 128; off > 0; off >>= 1) {
        if (tid < off) {
            float m2 = sm[tid + off], s2 = ssum[tid + off];
            float mm = fmaxf(m, m2);
            s = s * expf(m - mm) + s2 * expf(m2 - mm);
            m = mm;
            sm[tid] = m; ssum[tid] = s;
        }
        __syncthreads();
    }
    if (tid == 0) {
        float lse = m + logf(s);
        atomicAdd(out, (lse - t[row]) * (1.0f / (float)B_ROWS));
    }
}

// ================= fallback path (small ws): round-1 kernels =================
__global__ void w_norms(const float* __restrict__ w, float* __restrict__ winv) {
    int c    = blockIdx.x * 4 + (threadIdx.x >> 6);
    int lane = threadIdx.x & 63;
    const float4* wr = (const float4*)(w + (size_t)c * D_DIM);
    float4 a = wr[lane];
    float4 b = wr[lane + 64];
    float ss = a.x*a.x + a.y*a.y + a.z*a.z + a.w*a.w
             + b.x*b.x + b.y*b.y + b.z*b.z + b.w*b.w;
    #pragma unroll
    for (int m = 1; m < 64; m <<= 1) ss += __shfl_xor(ss, m);
    if (lane == 0) winv[c] = SCALE / fmaxf(sqrtf(ss), EPSN);
}

__global__ __launch_bounds__(256) void gemm_ce_f32(const unsigned short* __restrict__ xnb,
                                                   const float* __restrict__ w,
                                                   const float* __restrict__ winv,
                                                   float2* __restrict__ partials) {
    __shared__ unsigned short As[BM * BK];
    __shared__ unsigned short Bs[BN * BK];
    int tid = threadIdx.x;
    int m0 = blockIdx.x * BM, c0 = blockIdx.y * BN;
    int wid = tid >> 6, lane = tid & 63;
    int quad = lane >> 4, lr = lane & 15;
    int wr = wid >> 1, wc = wid & 1;
    f32x4 acc[4][4];
    #pragma unroll
    for (int i = 0; i < 4; i++)
        #pragma unroll
        for (int j = 0; j < 4; j++) {
            acc[i][j][0] = 0.f; acc[i][j][1] = 0.f; acc[i][j][2] = 0.f; acc[i][j][3] = 0.f;
        }
    int q = tid & 7, rbase = tid >> 3;
    for (int kt = 0; kt < D_DIM / BK; ++kt) {
        int k0 = kt * BK;
        __syncthreads();
        {
            int ch0 = tid, ch1 = tid + 256;
            uint4 v0 = *(const uint4*)(xnb + (size_t)(m0 + (ch0 >> 2)) * D_DIM + k0 + (ch0 & 3) * 8);
            uint4 v1 = *(const uint4*)(xnb + (size_t)(m0 + (ch1 >> 2)) * D_DIM + k0 + (ch1 & 3) * 8);
            ((uint4*)As)[ch0] = v0;
            ((uint4*)As)[ch1] = v1;
        }
        #pragma unroll
        for (int it = 0; it < 4; ++it) {
            int r = rbase + it * 32;
            int c = c0 + r;
            if (c >= C_CLS) c = C_CLS - 1;
            float4 wv = *(const float4*)(w + (size_t)c * D_DIM + k0 + q * 4);
            ushort4 o;
            o.x = f2bf(wv.x); o.y = f2bf(wv.y); o.z = f2bf(wv.z); o.w = f2bf(wv.w);
            *(ushort4*)(Bs + r * BK + q * 4) = o;
        }
        __syncthreads();
        bf16x8 af[4], bf[4];
        #pragma unroll
        for (int i = 0; i < 4; i++)
            af[i] = *(const bf16x8*)(As + (wr * 64 + i * 16 + lr) * BK + quad * 8);
        #pragma unroll
        for (int j = 0; j < 4; j++)
            bf[j] = *(const bf16x8*)(Bs + (wc * 64 + j * 16 + lr) * BK + quad * 8);
        #pragma unroll
        for (int i = 0; i < 4; i++)
            #pragma unroll
            for (int j = 0; j < 4; j++)
                acc[i][j] = __builtin_amdgcn_mfma_f32_16x16x32_bf16(af[i], bf[j], acc[i][j], 0, 0, 0);
    }
    float wv[4]; int valid[4];
    #pragma unroll
    for (int j = 0; j < 4; j++) {
        int cg = c0 + wc * 64 + j * 16 + lr;
        valid[j] = (cg < C_CLS);
        wv[j] = winv[valid[j] ? cg : (C_CLS - 1)];
    }
    int tile2 = blockIdx.y * 2 + wc;
    #pragma unroll
    for (int i = 0; i < 4; i++) {
        #pragma unroll
        for (int r = 0; r < 4; r++) {
            int row_g = m0 + wr * 64 + i * 16 + quad * 4 + r;
            float v0 = valid[0] ? acc[i][0][r] * wv[0] : -1e30f;
            float v1 = valid[1] ? acc[i][1][r] * wv[1] : -1e30f;
            float v2 = valid[2] ? acc[i][2][r] * wv[2] : -1e30f;
            float v3 = valid[3] ? acc[i][3][r] * wv[3] : -1e30f;
            float m = fmaxf(fmaxf(v0, v1), fmaxf(v2, v3));
            #pragma unroll
            for (int msk = 1; msk < 16; msk <<= 1) m = fmaxf(m, __shfl_xor(m, msk));
            float s = expf(v0 - m) + expf(v1 - m) + expf(v2 - m) + expf(v3 - m);
            #pragma unroll
            for (int msk = 1; msk < 16; msk <<= 1) s += __shfl_xor(s, msk);
            if (lr == 0)
                partials[(size_t)row_g * NT2 + tile2] = make_float2(m, s);
        }
    }
}

__global__ void label_logit_f32(const unsigned short* __restrict__ xnb,
                                const float* __restrict__ w,
                                const float* __restrict__ winv,
                                const int* __restrict__ label,
                                float* __restrict__ t) {
    int b = blockIdx.x;
    int lane = threadIdx.x;
    int lab = label[b];
    const float4*  wr = (const float4*)(w + (size_t)lab * D_DIM);
    const ushort4* xr = (const ushort4*)(xnb + (size_t)b * D_DIM);
    float dot = 0.f;
    #pragma unroll
    for (int k = 0; k < 2; k++) {
        float4  wv = wr[lane + 64 * k];
        ushort4 xv = xr[lane + 64 * k];
        dot += bf2f(xv.x) * wv.x + bf2f(xv.y) * wv.y + bf2f(xv.z) * wv.z + bf2f(xv.w) * wv.w;
    }
    #pragma unroll
    for (int m = 1; m < 64; m <<= 1) dot += __shfl_xor(dot, m);
    if (lane == 0) t[b] = dot * winv[lab];
}

extern "C" void kernel_launch(void* const* d_in, const int* in_sizes, int n_in,
                              void* d_out, int out_size, void* d_ws, size_t ws_size,
                              hipStream_t stream) {
    const float* x     = (const float*)d_in[0];
    const float* w     = (const float*)d_in[1];
    const int*   label = (const int*)d_in[2];
    float* out = (float*)d_out;

    char* ws = (char*)d_ws;
    unsigned short* xnb = (unsigned short*)ws;                 // 524288 B
    float* t            = (float*)(ws + 524288);               // 2048 B
    float2* partials    = (float2*)(ws + 526336);              // 6406144 B  (ends 6932480)
    unsigned short* wn  = (unsigned short*)(ws + 6932480);     // 102400000 B (ends 109332480)

    hipMemsetAsync(d_out, 0, sizeof(float), stream);
    normalize_x<<<B_ROWS, 64, 0, stream>>>(x, xnb);

    if (ws_size >= 109332480ULL) {
        w_prep<<<C_CLS / 4, 256, 0, stream>>>(w, wn);
        gemm_ce<<<dim3(4, NTILE), 256, 0, stream>>>(xnb, wn, partials);
        label_logit<<<B_ROWS, 64, 0, stream>>>(xnb, wn, label, t);
        reduce_loss<<<B_ROWS, 256, 0, stream>>>(partials, t, out);
    } else {
        float* winv      = (float*)(ws + 6932480);             // 400000 B
        w_norms<<<C_CLS / 4, 256, 0, stream>>>(w, winv);
        gemm_ce_f32<<<dim3(4, NTILE), 256, 0, stream>>>(xnb, w, winv, partials);
        label_logit_f32<<<B_ROWS, 64, 0, stream>>>(xnb, w, winv, label, t);
        reduce_loss<<<B_ROWS, 256, 0, stream>>>(partials, t, out);
    }
}